// Round 4
// baseline (782.169 us; speedup 1.0000x reference)
//
#include <hip/hip_runtime.h>
#include <math.h>

#define NL 2048
#define N2L 4096

typedef __attribute__((ext_vector_type(8))) short bf16x8;
typedef __attribute__((ext_vector_type(4))) float f32x4;
#define MFMA(a,b,c) __builtin_amdgcn_mfma_f32_16x16x32_bf16((a),(b),(c),0,0,0)

__device__ __forceinline__ unsigned short bf16_rne(float x){
  unsigned int u = __float_as_uint(x);
  u += 0x7FFFu + ((u>>16)&1u);
  return (unsigned short)(u>>16);
}
__device__ __forceinline__ float bf16_to_f(unsigned short h){
  return __uint_as_float(((unsigned int)h)<<16);
}

// ============================================================
// K0: split f32 inputs (q, k, Wq, Wkv) into hi/lo bf16 pairs.
// ============================================================
__global__ __launch_bounds__(256) void split_kernel(
    const float* __restrict__ q, const float* __restrict__ k,
    const float* __restrict__ Wq, const float* __restrict__ Wkv,
    unsigned short* __restrict__ qsh, unsigned short* __restrict__ qsl,
    unsigned short* __restrict__ ksh, unsigned short* __restrict__ ksl,
    unsigned short* __restrict__ wqh, unsigned short* __restrict__ wql,
    unsigned short* __restrict__ wkh, unsigned short* __restrict__ wkl) {
  const int C1 = 524288, C2 = 1048576, C3 = 1114112, C4 = 1245184;  // float4 counts
  for (int i = blockIdx.x * blockDim.x + threadIdx.x; i < C4; i += gridDim.x * blockDim.x) {
    const float* src; unsigned short *dh, *dl; int j;
    if (i < C1)      { src = q;   dh = qsh; dl = qsl; j = i; }
    else if (i < C2) { src = k;   dh = ksh; dl = ksl; j = i - C1; }
    else if (i < C3) { src = Wq;  dh = wqh; dl = wql; j = i - C2; }
    else             { src = Wkv; dh = wkh; dl = wkl; j = i - C3; }
    float4 v = reinterpret_cast<const float4*>(src)[j];
    unsigned short h0 = bf16_rne(v.x), h1 = bf16_rne(v.y), h2 = bf16_rne(v.z), h3 = bf16_rne(v.w);
    unsigned short l0 = bf16_rne(v.x - bf16_to_f(h0));
    unsigned short l1 = bf16_rne(v.y - bf16_to_f(h1));
    unsigned short l2 = bf16_rne(v.z - bf16_to_f(h2));
    unsigned short l3 = bf16_rne(v.w - bf16_to_f(h3));
    reinterpret_cast<uint2*>(dh)[j] = make_uint2((unsigned)h0 | ((unsigned)h1 << 16),
                                                 (unsigned)h2 | ((unsigned)h3 << 16));
    reinterpret_cast<uint2*>(dl)[j] = make_uint2((unsigned)l0 | ((unsigned)l1 << 16),
                                                 (unsigned)l2 | ((unsigned)l3 << 16));
  }
}

// ============================================================
// K1: r = sinusoid_table @ Wr^T, stored as hi/lo bf16 [4096][64]
// ============================================================
__global__ void build_r_kernel(const float* __restrict__ Wr,
                               unsigned short* __restrict__ rh,
                               unsigned short* __restrict__ rl) {
  int n = blockIdx.x;
  int t = threadIdx.x;  // 0..63
  __shared__ float pos[64];
  float v = 0.f;
  if (n != 0) {
    int j = t & 31;
    float inv = logf(10000.f) * (1.0f / 31.0f);
    float freq = expf(-inv * (float)j);
    float ang = (float)n * freq;
    v = (t < 32) ? sinf(ang) : cosf(ang);
  }
  pos[t] = v;
  __syncthreads();
  float acc = 0.f;
  const float* wrow = Wr + t * 64;
  #pragma unroll
  for (int j = 0; j < 64; ++j) acc += pos[j] * wrow[j];
  unsigned short hh = bf16_rne(acc);
  rh[n * 64 + t] = hh;
  rl[n * 64 + t] = bf16_rne(acc - bf16_to_f(hh));
}

// ============================================================
// K2: MFMA projections, 3-product split precision.
// by<16 (mode A): D[token][feat] = X @ W^T  -> qA/qB (with bias) or kh
// by>=16 (mode B): D'[feat][token] = Wv @ k^T -> vT (transposed V)
// ============================================================
__global__ __launch_bounds__(256) void proj_kernel(
    const unsigned short* __restrict__ qsh, const unsigned short* __restrict__ qsl,
    const unsigned short* __restrict__ ksh, const unsigned short* __restrict__ ksl,
    const unsigned short* __restrict__ wqh, const unsigned short* __restrict__ wql,
    const unsigned short* __restrict__ wkh, const unsigned short* __restrict__ wkl,
    const float* __restrict__ rrb, const float* __restrict__ rwb,
    unsigned short* __restrict__ qAh, unsigned short* __restrict__ qAl,
    unsigned short* __restrict__ qBh, unsigned short* __restrict__ qBl,
    unsigned short* __restrict__ khh, unsigned short* __restrict__ khl,
    unsigned short* __restrict__ vTh, unsigned short* __restrict__ vTl) {
  int tid = threadIdx.x;
  int w = tid >> 6, lane = tid & 63, li = lane & 15, g = lane >> 4;
  int bx = blockIdx.x, by = blockIdx.y;
  f32x4 acc[4];
  #pragma unroll
  for (int i = 0; i < 4; ++i) { acc[i][0]=0.f; acc[i][1]=0.f; acc[i][2]=0.f; acc[i][3]=0.f; }

  if (by < 16) {
    int n0 = by * 64, m0 = bx * 64;
    const unsigned short* Xh = (n0 < 512) ? qsh : ksh;
    const unsigned short* Xl = (n0 < 512) ? qsl : ksl;
    const unsigned short* Wh = (n0 < 512) ? (wqh + (size_t)n0 * 512) : (wkh + (size_t)(n0 - 512) * 512);
    const unsigned short* Wl = (n0 < 512) ? (wql + (size_t)n0 * 512) : (wkl + (size_t)(n0 - 512) * 512);
    int rowm = m0 + 16 * w + li;
    for (int ks = 0; ks < 16; ++ks) {
      int d0 = ks * 32 + 8 * g;
      bf16x8 ah = *(const bf16x8*)(Xh + (size_t)rowm * 512 + d0);
      bf16x8 al = *(const bf16x8*)(Xl + (size_t)rowm * 512 + d0);
      #pragma unroll
      for (int nt = 0; nt < 4; ++nt) {
        bf16x8 bh_ = *(const bf16x8*)(Wh + (size_t)(16 * nt + li) * 512 + d0);
        bf16x8 bl_ = *(const bf16x8*)(Wl + (size_t)(16 * nt + li) * 512 + d0);
        acc[nt] = MFMA(ah, bh_, acc[nt]);
        acc[nt] = MFMA(al, bh_, acc[nt]);
        acc[nt] = MFMA(ah, bl_, acc[nt]);
      }
    }
    if (n0 < 512) {
      int h = n0 >> 6;
      #pragma unroll
      for (int nt = 0; nt < 4; ++nt) {
        int d = 16 * nt + li;
        float rrv = rrb[h * 64 + d], rwv = rwb[h * 64 + d];
        #pragma unroll
        for (int r = 0; r < 4; ++r) {
          int m = m0 + 16 * w + 4 * g + r;
          int b = m >> 11, lt = m & 2047;
          size_t base = (((size_t)(b * 8 + h)) * 2048 + lt) * 64 + d;
          float a1 = acc[nt][r] + rrv;
          unsigned short h1 = bf16_rne(a1);
          qAh[base] = h1; qAl[base] = bf16_rne(a1 - bf16_to_f(h1));
          float a2 = acc[nt][r] + rwv;
          unsigned short h2 = bf16_rne(a2);
          qBh[base] = h2; qBl[base] = bf16_rne(a2 - bf16_to_f(h2));
        }
      }
    } else {
      int h = (n0 - 512) >> 6;
      #pragma unroll
      for (int nt = 0; nt < 4; ++nt) {
        int d = 16 * nt + li;
        #pragma unroll
        for (int r = 0; r < 4; ++r) {
          int m = m0 + 16 * w + 4 * g + r;
          int b = m >> 11, lt = m & 2047;
          size_t base = (((size_t)(b * 8 + h)) * 2048 + lt) * 64 + d;
          unsigned short h1 = bf16_rne(acc[nt][r]);
          khh[base] = h1; khl[base] = bf16_rne(acc[nt][r] - bf16_to_f(h1));
        }
      }
    }
  } else {
    int fy = by - 16, m0 = bx * 64, f0 = fy * 64;
    const unsigned short* Ah = wkh + (size_t)(512 + f0 + 16 * w + li) * 512;
    const unsigned short* Al = wkl + (size_t)(512 + f0 + 16 * w + li) * 512;
    for (int ks = 0; ks < 16; ++ks) {
      int d0 = ks * 32 + 8 * g;
      bf16x8 ah = *(const bf16x8*)(Ah + d0);
      bf16x8 al = *(const bf16x8*)(Al + d0);
      #pragma unroll
      for (int nt = 0; nt < 4; ++nt) {
        bf16x8 bh_ = *(const bf16x8*)(ksh + (size_t)(m0 + 16 * nt + li) * 512 + d0);
        bf16x8 bl_ = *(const bf16x8*)(ksl + (size_t)(m0 + 16 * nt + li) * 512 + d0);
        acc[nt] = MFMA(ah, bh_, acc[nt]);
        acc[nt] = MFMA(al, bh_, acc[nt]);
        acc[nt] = MFMA(ah, bl_, acc[nt]);
      }
    }
    int h = fy;
    #pragma unroll
    for (int nt = 0; nt < 4; ++nt) {
      int m = m0 + 16 * nt + li;
      int b = m >> 11, lt = m & 2047;
      #pragma unroll
      for (int r = 0; r < 4; ++r) {
        int d = 16 * w + 4 * g + r;
        size_t base = (((size_t)(b * 8 + h)) * 64 + d) * 2048 + lt;
        unsigned short h1 = bf16_rne(acc[nt][r]);
        vTh[base] = h1; vTl[base] = bf16_rne(acc[nt][r] - bf16_to_f(h1));
      }
    }
  }
}

// ============================================================
// K3: fused attention, two-pass flash with coalesced P write.
// Block = (32 q rows) x (b,h); 256 thr = 4 waves.
// Pass 1: S tiles via MFMA -> Slds (swizzled) -> coalesced role
//         reads S + mask, accumulates per-row (m,l). No global S write.
// Pass 2: recompute S tiles, p = exp(s-m)/l, coalesced global P write,
//         bf16 hi/lo P into swizzled Plds, PV via out^T = V^T . P^T.
// ============================================================
__global__ __launch_bounds__(256) void attn_kernel(
    const unsigned short* __restrict__ qAh, const unsigned short* __restrict__ qAl,
    const unsigned short* __restrict__ qBh, const unsigned short* __restrict__ qBl,
    const unsigned short* __restrict__ khh, const unsigned short* __restrict__ khl,
    const unsigned short* __restrict__ vTh, const unsigned short* __restrict__ vTl,
    const unsigned short* __restrict__ rh, const unsigned short* __restrict__ rl,
    const int* __restrict__ mask, float* __restrict__ outp, float* __restrict__ attnp) {
  __shared__ float Tlds[96 * 34];       // 13056 B
  __shared__ float Slds[2048];          // 8192 B, [32 rows][16 slots of 16B], slot ^= (row&7)
  __shared__ unsigned int Plds[2048];   // 8192 B: hi [0,4096), lo [4096,8192); rows of 128B

  int tid = threadIdx.x;
  int w = tid >> 6, lane = tid & 63, li = lane & 15, g = lane >> 4;
  int qlc = tid >> 3, jc = tid & 7, kc = jc * 8;   // coalesced role: row qlc, cols kc..kc+7
  int q0 = blockIdx.x * 32;
  int bh = blockIdx.y, b = bh >> 3, h = bh & 7;
  const unsigned short* qAhp = qAh + (size_t)bh * 131072;
  const unsigned short* qAlp = qAl + (size_t)bh * 131072;
  const unsigned short* qBhp = qBh + (size_t)bh * 131072;
  const unsigned short* qBlp = qBl + (size_t)bh * 131072;
  const unsigned short* khhp = khh + (size_t)bh * 131072;
  const unsigned short* khlp = khl + (size_t)bh * 131072;
  const unsigned short* vThp = vTh + (size_t)bh * 131072;
  const unsigned short* vTlp = vTl + (size_t)bh * 131072;
  const int* mrow = mask + (size_t)b * NL * NL + (size_t)(q0 + qlc) * NL;
  float* arow = attnp + (size_t)bh * NL * NL + (size_t)(q0 + qlc) * NL;

  // Q fragments (B operands), resident for whole kernel
  bf16x8 fAh[2][2], fAl[2][2], fBh[2][2], fBl[2][2];
  #pragma unroll
  for (int nt = 0; nt < 2; ++nt)
    #pragma unroll
    for (int ks = 0; ks < 2; ++ks) {
      size_t o = (size_t)(q0 + 16 * nt + li) * 64 + 32 * ks + 8 * g;
      fAh[nt][ks] = *(const bf16x8*)(qAhp + o);
      fAl[nt][ks] = *(const bf16x8*)(qAlp + o);
      fBh[nt][ks] = *(const bf16x8*)(qBhp + o);
      fBl[nt][ks] = *(const bf16x8*)(qBlp + o);
    }

  unsigned int sread0 = (unsigned)(qlc * 256 + (((2 * jc) * 16) ^ ((qlc & 7) << 4)));
  unsigned int sread1 = (unsigned)(qlc * 256 + (((2 * jc + 1) * 16) ^ ((qlc & 7) << 4)));

  // compute one 32q x 64k S tile into swizzled Slds (3 barriers)
  auto compute_s = [&](int kt) {
    int k0 = kt * 64;
    int krow = k0 + 16 * w + li;
    f32x4 accS[2];
    #pragma unroll
    for (int i = 0; i < 2; ++i) { accS[i][0]=0.f; accS[i][1]=0.f; accS[i][2]=0.f; accS[i][3]=0.f; }
    #pragma unroll
    for (int ks = 0; ks < 2; ++ks) {
      size_t o = (size_t)krow * 64 + 32 * ks + 8 * g;
      bf16x8 ah = *(const bf16x8*)(khhp + o);
      bf16x8 al = *(const bf16x8*)(khlp + o);
      #pragma unroll
      for (int nt = 0; nt < 2; ++nt) {
        accS[nt] = MFMA(ah, fAh[nt][ks], accS[nt]);
        accS[nt] = MFMA(al, fAh[nt][ks], accS[nt]);
        accS[nt] = MFMA(ah, fAl[nt][ks], accS[nt]);
      }
    }
    int nlo = k0 - q0 + 2017;
    f32x4 accT[3];
    #pragma unroll
    for (int i = 0; i < 3; ++i) { accT[i][0]=0.f; accT[i][1]=0.f; accT[i][2]=0.f; accT[i][3]=0.f; }
    #pragma unroll
    for (int pp = 0; pp < 3; ++pp) {
      int pi = w * 3 + pp, jt = pi >> 1, ntp = pi & 1;
      int rrow = nlo + jt * 16 + li;
      if (rrow > 4095) rrow = 4095;
      #pragma unroll
      for (int ks = 0; ks < 2; ++ks) {
        size_t o = (size_t)rrow * 64 + 32 * ks + 8 * g;
        bf16x8 ah = *(const bf16x8*)(rh + o);
        bf16x8 al = *(const bf16x8*)(rl + o);
        accT[pp] = MFMA(ah, fBh[ntp][ks], accT[pp]);
        accT[pp] = MFMA(al, fBh[ntp][ks], accT[pp]);
        accT[pp] = MFMA(ah, fBl[ntp][ks], accT[pp]);
      }
    }
    __syncthreads();                    // prior-iter Tlds/Slds/Plds reads done
    #pragma unroll
    for (int pp = 0; pp < 3; ++pp) {
      int pi = w * 3 + pp, jt = pi >> 1, ntp = pi & 1;
      #pragma unroll
      for (int r = 0; r < 4; ++r)
        Tlds[(jt * 16 + 4 * g + r) * 34 + ntp * 16 + li] = accT[pp][r];
    }
    __syncthreads();
    #pragma unroll
    for (int nt = 0; nt < 2; ++nt) {
      int ql_ = 16 * nt + li;
      float sv[4];
      #pragma unroll
      for (int r = 0; r < 4; ++r) {
        int kl = 16 * w + 4 * g + r;
        sv[r] = (accS[nt][r] + Tlds[(kl - ql_ + 31) * 34 + ql_]) * 0.125f;
      }
      unsigned int so = (unsigned)(ql_ * 256 + (((4 * w + g) * 16) ^ ((ql_ & 7) << 4)));
      *(float4*)((char*)Slds + so) = make_float4(sv[0], sv[1], sv[2], sv[3]);
    }
    __syncthreads();
  };

  // ---------------- pass 1: row stats ----------------
  float mrun = -3.0e38f, lrun = 0.f;    // per-thread; 8 threads share row qlc
  for (int kt = 0; kt < 32; ++kt) {
    compute_s(kt);
    int k0 = kt * 64;
    int4 m1 = *(const int4*)(mrow + k0 + kc);
    int4 m2 = *(const int4*)(mrow + k0 + kc + 4);
    float4 sa = *(const float4*)((const char*)Slds + sread0);
    float4 sb = *(const float4*)((const char*)Slds + sread1);
    float v0 = m1.x ? sa.x : -1e30f, v1 = m1.y ? sa.y : -1e30f;
    float v2 = m1.z ? sa.z : -1e30f, v3 = m1.w ? sa.w : -1e30f;
    float v4 = m2.x ? sb.x : -1e30f, v5 = m2.y ? sb.y : -1e30f;
    float v6 = m2.z ? sb.z : -1e30f, v7 = m2.w ? sb.w : -1e30f;
    float tmax = fmaxf(fmaxf(fmaxf(v0, v1), fmaxf(v2, v3)),
                       fmaxf(fmaxf(v4, v5), fmaxf(v6, v7)));
    tmax = fmaxf(tmax, __shfl_xor(tmax, 1));
    tmax = fmaxf(tmax, __shfl_xor(tmax, 2));
    tmax = fmaxf(tmax, __shfl_xor(tmax, 4));
    float ts = __expf(v0 - tmax) + __expf(v1 - tmax) + __expf(v2 - tmax) + __expf(v3 - tmax) +
               __expf(v4 - tmax) + __expf(v5 - tmax) + __expf(v6 - tmax) + __expf(v7 - tmax);
    ts += __shfl_xor(ts, 1);
    ts += __shfl_xor(ts, 2);
    ts += __shfl_xor(ts, 4);
    float mn = fmaxf(mrun, tmax);
    lrun = lrun * __expf(mrun - mn) + ts * __expf(tmax - mn);
    mrun = mn;
  }
  float mm = mrun, rlv = 1.0f / lrun;

  // ---------------- pass 2: P write + PV ----------------
  f32x4 accO[2];
  #pragma unroll
  for (int i = 0; i < 2; ++i) { accO[i][0]=0.f; accO[i][1]=0.f; accO[i][2]=0.f; accO[i][3]=0.f; }
  unsigned int woff = (unsigned)(qlc * 128 + ((kc * 2) ^ ((qlc & 7) << 4)));

  for (int kt = 0; kt < 32; ++kt) {
    compute_s(kt);
    int k0 = kt * 64;
    int4 m1 = *(const int4*)(mrow + k0 + kc);
    int4 m2 = *(const int4*)(mrow + k0 + kc + 4);
    float4 sa = *(const float4*)((const char*)Slds + sread0);
    float4 sb = *(const float4*)((const char*)Slds + sread1);
    float p0 = m1.x ? __expf(sa.x - mm) * rlv : 0.f;
    float p1 = m1.y ? __expf(sa.y - mm) * rlv : 0.f;
    float p2 = m1.z ? __expf(sa.z - mm) * rlv : 0.f;
    float p3 = m1.w ? __expf(sa.w - mm) * rlv : 0.f;
    float p4 = m2.x ? __expf(sb.x - mm) * rlv : 0.f;
    float p5 = m2.y ? __expf(sb.y - mm) * rlv : 0.f;
    float p6 = m2.z ? __expf(sb.z - mm) * rlv : 0.f;
    float p7 = m2.w ? __expf(sb.w - mm) * rlv : 0.f;
    *(float4*)(arow + k0 + kc) = make_float4(p0, p1, p2, p3);
    *(float4*)(arow + k0 + kc + 4) = make_float4(p4, p5, p6, p7);
    unsigned short h0 = bf16_rne(p0), h1 = bf16_rne(p1), h2 = bf16_rne(p2), h3 = bf16_rne(p3);
    unsigned short h4 = bf16_rne(p4), h5 = bf16_rne(p5), h6 = bf16_rne(p6), h7 = bf16_rne(p7);
    unsigned short e0 = bf16_rne(p0 - bf16_to_f(h0)), e1 = bf16_rne(p1 - bf16_to_f(h1));
    unsigned short e2 = bf16_rne(p2 - bf16_to_f(h2)), e3 = bf16_rne(p3 - bf16_to_f(h3));
    unsigned short e4 = bf16_rne(p4 - bf16_to_f(h4)), e5 = bf16_rne(p5 - bf16_to_f(h5));
    unsigned short e6 = bf16_rne(p6 - bf16_to_f(h6)), e7 = bf16_rne(p7 - bf16_to_f(h7));
    *(uint4*)((char*)Plds + woff) =
        make_uint4((unsigned)h0 | ((unsigned)h1 << 16), (unsigned)h2 | ((unsigned)h3 << 16),
                   (unsigned)h4 | ((unsigned)h5 << 16), (unsigned)h6 | ((unsigned)h7 << 16));
    *(uint4*)((char*)Plds + 4096 + woff) =
        make_uint4((unsigned)e0 | ((unsigned)e1 << 16), (unsigned)e2 | ((unsigned)e3 << 16),
                   (unsigned)e4 | ((unsigned)e5 << 16), (unsigned)e6 | ((unsigned)e7 << 16));
    __syncthreads();
    #pragma unroll
    for (int ks = 0; ks < 2; ++ks) {
      size_t vo = (size_t)(16 * w + li) * NL + k0 + 32 * ks + 8 * g;
      bf16x8 vh_ = *(const bf16x8*)(vThp + vo);
      bf16x8 vl_ = *(const bf16x8*)(vTlp + vo);
      #pragma unroll
      for (int nt = 0; nt < 2; ++nt) {
        unsigned int ro = (unsigned)((16 * nt + li) * 128 + (((32 * ks + 8 * g) * 2) ^ ((li & 7) << 4)));
        bf16x8 ph = *(const bf16x8*)((const char*)Plds + ro);
        bf16x8 pl = *(const bf16x8*)((const char*)Plds + 4096 + ro);
        accO[nt] = MFMA(vh_, ph, accO[nt]);
        accO[nt] = MFMA(vl_, ph, accO[nt]);
        accO[nt] = MFMA(vh_, pl, accO[nt]);
      }
    }
  }
  #pragma unroll
  for (int nt = 0; nt < 2; ++nt) {
    int qg = q0 + 16 * nt + li;
    int d = 16 * w + 4 * g;
    *(float4*)(outp + ((size_t)b * NL + qg) * 512 + h * 64 + d) =
        make_float4(accO[nt][0], accO[nt][1], accO[nt][2], accO[nt][3]);
  }
}

// ============================================================
extern "C" void kernel_launch(void* const* d_in, const int* in_sizes, int n_in,
                              void* d_out, int out_size, void* d_ws, size_t ws_size,
                              hipStream_t stream) {
  const float* q    = (const float*)d_in[0];
  const float* k    = (const float*)d_in[1];
  const int*   mask = (const int*)d_in[2];
  const float* Wq   = (const float*)d_in[3];
  const float* Wkv  = (const float*)d_in[4];
  const float* Wr   = (const float*)d_in[5];
  const float* rrb  = (const float*)d_in[6];
  const float* rwb  = (const float*)d_in[7];

  float* outp  = (float*)d_out;                 // [2,2048,512]
  float* attnp = outp + (size_t)2 * NL * 512;   // [2,8,2048,2048]

  unsigned short* W = (unsigned short*)d_ws;
  const size_t RHI = 0,            RLO = RHI + 262144;
  const size_t QSH = RLO + 262144, QSL = QSH + 2097152;
  const size_t KSH = QSL + 2097152, KSL = KSH + 2097152;
  const size_t WQH = KSL + 2097152, WQL = WQH + 262144;
  const size_t WKH = WQL + 262144,  WKL = WKH + 524288;
  const size_t QAH = WKL + 524288,  QAL = QAH + 2097152;
  const size_t QBH = QAL + 2097152, QBL = QBH + 2097152;
  const size_t KHH = QBL + 2097152, KHL = KHH + 2097152;
  const size_t VTH = KHL + 2097152, VTL = VTH + 2097152;

  hipLaunchKernelGGL(split_kernel, dim3(1024), dim3(256), 0, stream,
                     q, k, Wq, Wkv, W+QSH, W+QSL, W+KSH, W+KSL, W+WQH, W+WQL, W+WKH, W+WKL);
  hipLaunchKernelGGL(build_r_kernel, dim3(N2L), dim3(64), 0, stream, Wr, W+RHI, W+RLO);
  hipLaunchKernelGGL(proj_kernel, dim3(64, 24), dim3(256), 0, stream,
                     W+QSH, W+QSL, W+KSH, W+KSL, W+WQH, W+WQL, W+WKH, W+WKL, rrb, rwb,
                     W+QAH, W+QAL, W+QBH, W+QBL, W+KHH, W+KHL, W+VTH, W+VTL);
  hipLaunchKernelGGL(attn_kernel, dim3(64, 16), dim3(256), 0, stream,
                     W+QAH, W+QAL, W+QBH, W+QBL, W+KHH, W+KHL, W+VTH, W+VTL,
                     W+RHI, W+RLO, mask, outp, attnp);
}

// Round 5
// 570.204 us; speedup vs baseline: 1.3717x; 1.3717x over previous
//
#include <hip/hip_runtime.h>
#include <math.h>

#define NL 2048
#define N2L 4096

typedef __attribute__((ext_vector_type(8))) short bf16x8;
typedef __attribute__((ext_vector_type(4))) float f32x4;
#define MFMA(a,b,c) __builtin_amdgcn_mfma_f32_16x16x32_bf16((a),(b),(c),0,0,0)

// LDS-only barrier: waits DS ops, leaves global loads/stores in flight.
#define BARRIER() do {                                        \
    __builtin_amdgcn_sched_barrier(0);                        \
    asm volatile("s_waitcnt lgkmcnt(0)" ::: "memory");        \
    __builtin_amdgcn_s_barrier();                             \
    __builtin_amdgcn_sched_barrier(0);                        \
  } while (0)

__device__ __forceinline__ unsigned short bf16_rne(float x){
  unsigned int u = __float_as_uint(x);
  u += 0x7FFFu + ((u>>16)&1u);
  return (unsigned short)(u>>16);
}
__device__ __forceinline__ float bf16_to_f(unsigned short h){
  return __uint_as_float(((unsigned int)h)<<16);
}

// ============================================================
// K0: split f32 inputs (q, k, Wq, Wkv) into hi/lo bf16 pairs.
// ============================================================
__global__ __launch_bounds__(256) void split_kernel(
    const float* __restrict__ q, const float* __restrict__ k,
    const float* __restrict__ Wq, const float* __restrict__ Wkv,
    unsigned short* __restrict__ qsh, unsigned short* __restrict__ qsl,
    unsigned short* __restrict__ ksh, unsigned short* __restrict__ ksl,
    unsigned short* __restrict__ wqh, unsigned short* __restrict__ wql,
    unsigned short* __restrict__ wkh, unsigned short* __restrict__ wkl) {
  const int C1 = 524288, C2 = 1048576, C3 = 1114112, C4 = 1245184;  // float4 counts
  for (int i = blockIdx.x * blockDim.x + threadIdx.x; i < C4; i += gridDim.x * blockDim.x) {
    const float* src; unsigned short *dh, *dl; int j;
    if (i < C1)      { src = q;   dh = qsh; dl = qsl; j = i; }
    else if (i < C2) { src = k;   dh = ksh; dl = ksl; j = i - C1; }
    else if (i < C3) { src = Wq;  dh = wqh; dl = wql; j = i - C2; }
    else             { src = Wkv; dh = wkh; dl = wkl; j = i - C3; }
    float4 v = reinterpret_cast<const float4*>(src)[j];
    unsigned short h0 = bf16_rne(v.x), h1 = bf16_rne(v.y), h2 = bf16_rne(v.z), h3 = bf16_rne(v.w);
    unsigned short l0 = bf16_rne(v.x - bf16_to_f(h0));
    unsigned short l1 = bf16_rne(v.y - bf16_to_f(h1));
    unsigned short l2 = bf16_rne(v.z - bf16_to_f(h2));
    unsigned short l3 = bf16_rne(v.w - bf16_to_f(h3));
    reinterpret_cast<uint2*>(dh)[j] = make_uint2((unsigned)h0 | ((unsigned)h1 << 16),
                                                 (unsigned)h2 | ((unsigned)h3 << 16));
    reinterpret_cast<uint2*>(dl)[j] = make_uint2((unsigned)l0 | ((unsigned)l1 << 16),
                                                 (unsigned)l2 | ((unsigned)l3 << 16));
  }
}

// ============================================================
// K1: r = sinusoid_table @ Wr^T, stored as hi/lo bf16 [4096][64]
// ============================================================
__global__ void build_r_kernel(const float* __restrict__ Wr,
                               unsigned short* __restrict__ rh,
                               unsigned short* __restrict__ rl) {
  int n = blockIdx.x;
  int t = threadIdx.x;  // 0..63
  __shared__ float pos[64];
  float v = 0.f;
  if (n != 0) {
    int j = t & 31;
    float inv = logf(10000.f) * (1.0f / 31.0f);
    float freq = expf(-inv * (float)j);
    float ang = (float)n * freq;
    v = (t < 32) ? sinf(ang) : cosf(ang);
  }
  pos[t] = v;
  __syncthreads();
  float acc = 0.f;
  const float* wrow = Wr + t * 64;
  #pragma unroll
  for (int j = 0; j < 64; ++j) acc += pos[j] * wrow[j];
  unsigned short hh = bf16_rne(acc);
  rh[n * 64 + t] = hh;
  rl[n * 64 + t] = bf16_rne(acc - bf16_to_f(hh));
}

// ============================================================
// K2: MFMA projections, 3-product split precision.
// ============================================================
__global__ __launch_bounds__(256) void proj_kernel(
    const unsigned short* __restrict__ qsh, const unsigned short* __restrict__ qsl,
    const unsigned short* __restrict__ ksh, const unsigned short* __restrict__ ksl,
    const unsigned short* __restrict__ wqh, const unsigned short* __restrict__ wql,
    const unsigned short* __restrict__ wkh, const unsigned short* __restrict__ wkl,
    const float* __restrict__ rrb, const float* __restrict__ rwb,
    unsigned short* __restrict__ qAh, unsigned short* __restrict__ qAl,
    unsigned short* __restrict__ qBh, unsigned short* __restrict__ qBl,
    unsigned short* __restrict__ khh, unsigned short* __restrict__ khl,
    unsigned short* __restrict__ vTh, unsigned short* __restrict__ vTl) {
  int tid = threadIdx.x;
  int w = tid >> 6, lane = tid & 63, li = lane & 15, g = lane >> 4;
  int bx = blockIdx.x, by = blockIdx.y;
  f32x4 acc[4];
  #pragma unroll
  for (int i = 0; i < 4; ++i) { acc[i][0]=0.f; acc[i][1]=0.f; acc[i][2]=0.f; acc[i][3]=0.f; }

  if (by < 16) {
    int n0 = by * 64, m0 = bx * 64;
    const unsigned short* Xh = (n0 < 512) ? qsh : ksh;
    const unsigned short* Xl = (n0 < 512) ? qsl : ksl;
    const unsigned short* Wh = (n0 < 512) ? (wqh + (size_t)n0 * 512) : (wkh + (size_t)(n0 - 512) * 512);
    const unsigned short* Wl = (n0 < 512) ? (wql + (size_t)n0 * 512) : (wkl + (size_t)(n0 - 512) * 512);
    int rowm = m0 + 16 * w + li;
    for (int ks = 0; ks < 16; ++ks) {
      int d0 = ks * 32 + 8 * g;
      bf16x8 ah = *(const bf16x8*)(Xh + (size_t)rowm * 512 + d0);
      bf16x8 al = *(const bf16x8*)(Xl + (size_t)rowm * 512 + d0);
      #pragma unroll
      for (int nt = 0; nt < 4; ++nt) {
        bf16x8 bh_ = *(const bf16x8*)(Wh + (size_t)(16 * nt + li) * 512 + d0);
        bf16x8 bl_ = *(const bf16x8*)(Wl + (size_t)(16 * nt + li) * 512 + d0);
        acc[nt] = MFMA(ah, bh_, acc[nt]);
        acc[nt] = MFMA(al, bh_, acc[nt]);
        acc[nt] = MFMA(ah, bl_, acc[nt]);
      }
    }
    if (n0 < 512) {
      int h = n0 >> 6;
      #pragma unroll
      for (int nt = 0; nt < 4; ++nt) {
        int d = 16 * nt + li;
        float rrv = rrb[h * 64 + d], rwv = rwb[h * 64 + d];
        #pragma unroll
        for (int r = 0; r < 4; ++r) {
          int m = m0 + 16 * w + 4 * g + r;
          int b = m >> 11, lt = m & 2047;
          size_t base = (((size_t)(b * 8 + h)) * 2048 + lt) * 64 + d;
          float a1 = acc[nt][r] + rrv;
          unsigned short h1 = bf16_rne(a1);
          qAh[base] = h1; qAl[base] = bf16_rne(a1 - bf16_to_f(h1));
          float a2 = acc[nt][r] + rwv;
          unsigned short h2 = bf16_rne(a2);
          qBh[base] = h2; qBl[base] = bf16_rne(a2 - bf16_to_f(h2));
        }
      }
    } else {
      int h = (n0 - 512) >> 6;
      #pragma unroll
      for (int nt = 0; nt < 4; ++nt) {
        int d = 16 * nt + li;
        #pragma unroll
        for (int r = 0; r < 4; ++r) {
          int m = m0 + 16 * w + 4 * g + r;
          int b = m >> 11, lt = m & 2047;
          size_t base = (((size_t)(b * 8 + h)) * 2048 + lt) * 64 + d;
          unsigned short h1 = bf16_rne(acc[nt][r]);
          khh[base] = h1; khl[base] = bf16_rne(acc[nt][r] - bf16_to_f(h1));
        }
      }
    }
  } else {
    int fy = by - 16, m0 = bx * 64, f0 = fy * 64;
    const unsigned short* Ah = wkh + (size_t)(512 + f0 + 16 * w + li) * 512;
    const unsigned short* Al = wkl + (size_t)(512 + f0 + 16 * w + li) * 512;
    for (int ks = 0; ks < 16; ++ks) {
      int d0 = ks * 32 + 8 * g;
      bf16x8 ah = *(const bf16x8*)(Ah + d0);
      bf16x8 al = *(const bf16x8*)(Al + d0);
      #pragma unroll
      for (int nt = 0; nt < 4; ++nt) {
        bf16x8 bh_ = *(const bf16x8*)(ksh + (size_t)(m0 + 16 * nt + li) * 512 + d0);
        bf16x8 bl_ = *(const bf16x8*)(ksl + (size_t)(m0 + 16 * nt + li) * 512 + d0);
        acc[nt] = MFMA(ah, bh_, acc[nt]);
        acc[nt] = MFMA(al, bh_, acc[nt]);
        acc[nt] = MFMA(ah, bl_, acc[nt]);
      }
    }
    int h = fy;
    #pragma unroll
    for (int nt = 0; nt < 4; ++nt) {
      int m = m0 + 16 * nt + li;
      int b = m >> 11, lt = m & 2047;
      #pragma unroll
      for (int r = 0; r < 4; ++r) {
        int d = 16 * w + 4 * g + r;
        size_t base = (((size_t)(b * 8 + h)) * 64 + d) * 2048 + lt;
        unsigned short h1 = bf16_rne(acc[nt][r]);
        vTh[base] = h1; vTl[base] = bf16_rne(acc[nt][r] - bf16_to_f(h1));
      }
    }
  }
}

// ============================================================
// K3: single-pass attention (no max subtraction: scores are O(8), exp-safe).
// Per tile: S via MFMA -> Slds; p~ = mask ? exp(s) : 0; coalesced global
// write of p~; l += sum(p~); p~ -> bf16 hi/lo Plds; PV accO += V^T.P^T.
// Final: out = accO / l. attn normalized by the rescale kernel.
// LDS-only raw barriers: global loads/stores stay in flight.
// ============================================================
__global__ __launch_bounds__(256) void attn_kernel(
    const unsigned short* __restrict__ qAh, const unsigned short* __restrict__ qAl,
    const unsigned short* __restrict__ qBh, const unsigned short* __restrict__ qBl,
    const unsigned short* __restrict__ khh, const unsigned short* __restrict__ khl,
    const unsigned short* __restrict__ vTh, const unsigned short* __restrict__ vTl,
    const unsigned short* __restrict__ rh, const unsigned short* __restrict__ rl,
    const int* __restrict__ mask, float* __restrict__ outp, float* __restrict__ attnp,
    float* __restrict__ rlbuf) {
  __shared__ float Tlds[96 * 34];       // 13056 B
  __shared__ float Slds[2048];          // 8192 B swizzled [32 rows][16 slots], slot ^= row&7
  __shared__ unsigned int Plds[2048];   // 8192 B: hi [0,4096), lo [4096,8192)
  __shared__ float rlf[32];

  int tid = threadIdx.x;
  int w = tid >> 6, lane = tid & 63, li = lane & 15, g = lane >> 4;
  int qlc = tid >> 3, jc = tid & 7, kc = jc * 8;   // coalesced role
  int q0 = blockIdx.x * 32;
  int bh = blockIdx.y, b = bh >> 3, h = bh & 7;
  const unsigned short* qAhp = qAh + (size_t)bh * 131072;
  const unsigned short* qAlp = qAl + (size_t)bh * 131072;
  const unsigned short* qBhp = qBh + (size_t)bh * 131072;
  const unsigned short* qBlp = qBl + (size_t)bh * 131072;
  const unsigned short* khhp = khh + (size_t)bh * 131072;
  const unsigned short* khlp = khl + (size_t)bh * 131072;
  const unsigned short* vThp = vTh + (size_t)bh * 131072;
  const unsigned short* vTlp = vTl + (size_t)bh * 131072;
  const int* mrow = mask + (size_t)b * NL * NL + (size_t)(q0 + qlc) * NL;
  float* arow = attnp + (size_t)bh * NL * NL + (size_t)(q0 + qlc) * NL;

  // Q fragments (B operands), resident for whole kernel
  bf16x8 fAh[2][2], fAl[2][2], fBh[2][2], fBl[2][2];
  #pragma unroll
  for (int nt = 0; nt < 2; ++nt)
    #pragma unroll
    for (int ks = 0; ks < 2; ++ks) {
      size_t o = (size_t)(q0 + 16 * nt + li) * 64 + 32 * ks + 8 * g;
      fAh[nt][ks] = *(const bf16x8*)(qAhp + o);
      fAl[nt][ks] = *(const bf16x8*)(qAlp + o);
      fBh[nt][ks] = *(const bf16x8*)(qBhp + o);
      fBl[nt][ks] = *(const bf16x8*)(qBlp + o);
    }

  unsigned int sread0 = (unsigned)(qlc * 256 + (((2 * jc) * 16) ^ ((qlc & 7) << 4)));
  unsigned int sread1 = (unsigned)(qlc * 256 + (((2 * jc + 1) * 16) ^ ((qlc & 7) << 4)));
  unsigned int woff = (unsigned)(qlc * 128 + ((kc * 2) ^ ((qlc & 7) << 4)));

  float lrun = 0.f;
  f32x4 accO[2];
  #pragma unroll
  for (int i = 0; i < 2; ++i) { accO[i][0]=0.f; accO[i][1]=0.f; accO[i][2]=0.f; accO[i][3]=0.f; }

  for (int kt = 0; kt < 32; ++kt) {
    int k0 = kt * 64;
    // ---- issue this tile's mask + V loads early (used after 2-3 barriers)
    int4 mv1 = *(const int4*)(mrow + k0 + kc);
    int4 mv2 = *(const int4*)(mrow + k0 + kc + 4);
    bf16x8 vhf[2], vlf[2];
    #pragma unroll
    for (int ks = 0; ks < 2; ++ks) {
      size_t vo = (size_t)(16 * w + li) * NL + k0 + 32 * ks + 8 * g;
      vhf[ks] = *(const bf16x8*)(vThp + vo);
      vlf[ks] = *(const bf16x8*)(vTlp + vo);
    }
    // ---- P1: S and T MFMAs
    int krow = k0 + 16 * w + li;
    f32x4 accS[2];
    #pragma unroll
    for (int i = 0; i < 2; ++i) { accS[i][0]=0.f; accS[i][1]=0.f; accS[i][2]=0.f; accS[i][3]=0.f; }
    #pragma unroll
    for (int ks = 0; ks < 2; ++ks) {
      size_t o = (size_t)krow * 64 + 32 * ks + 8 * g;
      bf16x8 ah = *(const bf16x8*)(khhp + o);
      bf16x8 al = *(const bf16x8*)(khlp + o);
      #pragma unroll
      for (int nt = 0; nt < 2; ++nt) {
        accS[nt] = MFMA(ah, fAh[nt][ks], accS[nt]);
        accS[nt] = MFMA(al, fAh[nt][ks], accS[nt]);
        accS[nt] = MFMA(ah, fAl[nt][ks], accS[nt]);
      }
    }
    int nlo = k0 - q0 + 2017;
    f32x4 accT[3];
    #pragma unroll
    for (int i = 0; i < 3; ++i) { accT[i][0]=0.f; accT[i][1]=0.f; accT[i][2]=0.f; accT[i][3]=0.f; }
    #pragma unroll
    for (int pp = 0; pp < 3; ++pp) {
      int pi = w * 3 + pp, jt = pi >> 1, ntp = pi & 1;
      int rrow = nlo + jt * 16 + li;
      if (rrow > 4095) rrow = 4095;
      #pragma unroll
      for (int ks = 0; ks < 2; ++ks) {
        size_t o = (size_t)rrow * 64 + 32 * ks + 8 * g;
        bf16x8 ah = *(const bf16x8*)(rh + o);
        bf16x8 al = *(const bf16x8*)(rl + o);
        accT[pp] = MFMA(ah, fBh[ntp][ks], accT[pp]);
        accT[pp] = MFMA(al, fBh[ntp][ks], accT[pp]);
        accT[pp] = MFMA(ah, fBl[ntp][ks], accT[pp]);
      }
    }
    // ---- P2: T band -> Tlds (prior-tile Tlds/Slds/Plds readers done: >=1 barrier ago)
    #pragma unroll
    for (int pp = 0; pp < 3; ++pp) {
      int pi = w * 3 + pp, jt = pi >> 1, ntp = pi & 1;
      #pragma unroll
      for (int r = 0; r < 4; ++r)
        Tlds[(jt * 16 + 4 * g + r) * 34 + ntp * 16 + li] = accT[pp][r];
    }
    BARRIER();
    // ---- P3: gather + Slds write
    #pragma unroll
    for (int nt = 0; nt < 2; ++nt) {
      int ql_ = 16 * nt + li;
      float sv[4];
      #pragma unroll
      for (int r = 0; r < 4; ++r) {
        int kl = 16 * w + 4 * g + r;
        sv[r] = (accS[nt][r] + Tlds[(kl - ql_ + 31) * 34 + ql_]) * 0.125f;
      }
      unsigned int so = (unsigned)(ql_ * 256 + (((4 * w + g) * 16) ^ ((ql_ & 7) << 4)));
      *(float4*)((char*)Slds + so) = make_float4(sv[0], sv[1], sv[2], sv[3]);
    }
    BARRIER();
    // ---- P4: coalesced role: p~ = mask ? exp(s) : 0; write; l; Plds
    float4 sa = *(const float4*)((const char*)Slds + sread0);
    float4 sb = *(const float4*)((const char*)Slds + sread1);
    float p0 = mv1.x ? __expf(sa.x) : 0.f;
    float p1 = mv1.y ? __expf(sa.y) : 0.f;
    float p2 = mv1.z ? __expf(sa.z) : 0.f;
    float p3 = mv1.w ? __expf(sa.w) : 0.f;
    float p4 = mv2.x ? __expf(sb.x) : 0.f;
    float p5 = mv2.y ? __expf(sb.y) : 0.f;
    float p6 = mv2.z ? __expf(sb.z) : 0.f;
    float p7 = mv2.w ? __expf(sb.w) : 0.f;
    *(float4*)(arow + k0 + kc) = make_float4(p0, p1, p2, p3);
    *(float4*)(arow + k0 + kc + 4) = make_float4(p4, p5, p6, p7);
    float ts = p0 + p1 + p2 + p3 + p4 + p5 + p6 + p7;
    ts += __shfl_xor(ts, 1);
    ts += __shfl_xor(ts, 2);
    ts += __shfl_xor(ts, 4);
    lrun += ts;
    unsigned short h0 = bf16_rne(p0), h1 = bf16_rne(p1), h2 = bf16_rne(p2), h3 = bf16_rne(p3);
    unsigned short h4 = bf16_rne(p4), h5 = bf16_rne(p5), h6 = bf16_rne(p6), h7 = bf16_rne(p7);
    unsigned short e0 = bf16_rne(p0 - bf16_to_f(h0)), e1 = bf16_rne(p1 - bf16_to_f(h1));
    unsigned short e2 = bf16_rne(p2 - bf16_to_f(h2)), e3 = bf16_rne(p3 - bf16_to_f(h3));
    unsigned short e4 = bf16_rne(p4 - bf16_to_f(h4)), e5 = bf16_rne(p5 - bf16_to_f(h5));
    unsigned short e6 = bf16_rne(p6 - bf16_to_f(h6)), e7 = bf16_rne(p7 - bf16_to_f(h7));
    *(uint4*)((char*)Plds + woff) =
        make_uint4((unsigned)h0 | ((unsigned)h1 << 16), (unsigned)h2 | ((unsigned)h3 << 16),
                   (unsigned)h4 | ((unsigned)h5 << 16), (unsigned)h6 | ((unsigned)h7 << 16));
    *(uint4*)((char*)Plds + 4096 + woff) =
        make_uint4((unsigned)e0 | ((unsigned)e1 << 16), (unsigned)e2 | ((unsigned)e3 << 16),
                   (unsigned)e4 | ((unsigned)e5 << 16), (unsigned)e6 | ((unsigned)e7 << 16));
    BARRIER();
    // ---- P5: PV
    #pragma unroll
    for (int ks = 0; ks < 2; ++ks) {
      #pragma unroll
      for (int nt = 0; nt < 2; ++nt) {
        unsigned int ro = (unsigned)((16 * nt + li) * 128 + (((32 * ks + 8 * g) * 2) ^ ((li & 7) << 4)));
        bf16x8 ph = *(const bf16x8*)((const char*)Plds + ro);
        bf16x8 pl = *(const bf16x8*)((const char*)Plds + 4096 + ro);
        accO[nt] = MFMA(vhf[ks], ph, accO[nt]);
        accO[nt] = MFMA(vlf[ks], ph, accO[nt]);
        accO[nt] = MFMA(vhf[ks], pl, accO[nt]);
      }
    }
    BARRIER();
  }

  // ---- epilogue: rl broadcast, out = accO * rl, rl -> global
  if (jc == 0) {
    float rv = 1.0f / lrun;
    rlf[qlc] = rv;
    rlbuf[(size_t)bh * NL + q0 + qlc] = rv;
  }
  BARRIER();
  float r0 = rlf[li], r1 = rlf[16 + li];
  #pragma unroll
  for (int nt = 0; nt < 2; ++nt) {
    float rn = nt ? r1 : r0;
    int qg = q0 + 16 * nt + li;
    int d = 16 * w + 4 * g;
    *(float4*)(outp + ((size_t)b * NL + qg) * 512 + h * 64 + d) =
        make_float4(accO[nt][0] * rn, accO[nt][1] * rn, accO[nt][2] * rn, accO[nt][3] * rn);
  }
}

// ============================================================
// K4: attn[bh][q][:] *= rl[bh][q]  (coalesced stream)
// ============================================================
__global__ __launch_bounds__(256) void rescale_kernel(
    const float* __restrict__ rlbuf, float* __restrict__ attnp) {
  int row = blockIdx.x;
  int bh = blockIdx.y;
  float rv = rlbuf[(size_t)bh * NL + row];
  float* ap = attnp + ((size_t)bh * NL + row) * NL + threadIdx.x * 8;
  float4 a = *(float4*)ap;
  float4 b2 = *(float4*)(ap + 4);
  *(float4*)ap = make_float4(a.x * rv, a.y * rv, a.z * rv, a.w * rv);
  *(float4*)(ap + 4) = make_float4(b2.x * rv, b2.y * rv, b2.z * rv, b2.w * rv);
}

// ============================================================
extern "C" void kernel_launch(void* const* d_in, const int* in_sizes, int n_in,
                              void* d_out, int out_size, void* d_ws, size_t ws_size,
                              hipStream_t stream) {
  const float* q    = (const float*)d_in[0];
  const float* k    = (const float*)d_in[1];
  const int*   mask = (const int*)d_in[2];
  const float* Wq   = (const float*)d_in[3];
  const float* Wkv  = (const float*)d_in[4];
  const float* Wr   = (const float*)d_in[5];
  const float* rrb  = (const float*)d_in[6];
  const float* rwb  = (const float*)d_in[7];

  float* outp  = (float*)d_out;                 // [2,2048,512]
  float* attnp = outp + (size_t)2 * NL * 512;   // [2,8,2048,2048]

  unsigned short* W = (unsigned short*)d_ws;
  const size_t RHI = 0,            RLO = RHI + 262144;
  const size_t QSH = RLO + 262144, QSL = QSH + 2097152;
  const size_t KSH = QSL + 2097152, KSL = KSH + 2097152;
  const size_t WQH = KSL + 2097152, WQL = WQH + 262144;
  const size_t WKH = WQL + 262144,  WKL = WKH + 524288;
  const size_t QAH = WKL + 524288,  QAL = QAH + 2097152;
  const size_t QBH = QAL + 2097152, QBL = QBH + 2097152;
  const size_t KHH = QBL + 2097152, KHL = KHH + 2097152;
  const size_t VTH = KHL + 2097152, VTL = VTH + 2097152;
  const size_t RLB = VTL + 2097152;             // float[16*2048]
  float* rlbuf = (float*)(W + RLB);

  hipLaunchKernelGGL(split_kernel, dim3(1024), dim3(256), 0, stream,
                     q, k, Wq, Wkv, W+QSH, W+QSL, W+KSH, W+KSL, W+WQH, W+WQL, W+WKH, W+WKL);
  hipLaunchKernelGGL(build_r_kernel, dim3(N2L), dim3(64), 0, stream, Wr, W+RHI, W+RLO);
  hipLaunchKernelGGL(proj_kernel, dim3(64, 24), dim3(256), 0, stream,
                     W+QSH, W+QSL, W+KSH, W+KSL, W+WQH, W+WQL, W+WKH, W+WKL, rrb, rwb,
                     W+QAH, W+QAL, W+QBH, W+QBL, W+KHH, W+KHL, W+VTH, W+VTL);
  hipLaunchKernelGGL(attn_kernel, dim3(64, 16), dim3(256), 0, stream,
                     W+QAH, W+QAL, W+QBH, W+QBL, W+KHH, W+KHL, W+VTH, W+VTL,
                     W+RHI, W+RLO, mask, outp, attnp, rlbuf);
  hipLaunchKernelGGL(rescale_kernel, dim3(NL, 16), dim3(256), 0, stream,
                     rlbuf, attnp);
}